// Round 11
// baseline (132.283 us; speedup 1.0000x reference)
//
#include <hip/hip_runtime.h>
#include <hip/hip_bf16.h>
#include <math.h>

// FC-CapsNet routing: u[128,1152,8], W[1152,32,8,16], b[1152,32] -> v[128,32,16]
// R11: break the 4-waves/SIMD wall. Partials stored as bf16 (RNE): 24 MB at
// NCHUNK=192 (<32MB L2 agg, no R7 write-thrash) -> grid (192,8)=1536 blocks
// = 6 blocks/CU = 6 waves/SIMD (R10 was 4). Skeleton unchanged from R8/R10:
// no LDS tile, no barriers, direct-global coalesced W reads (L3/L2-cached),
// scalar u loads, stage-major max-free softmax, 2x8-b128 W load batches.
// NOTE (profiling): dur_us includes fixed ~50us harness cost (256MiB d_ws
// 0xAA poison fill ~45us + d_in restore ~4us) as fillBufferAligned rows.

#define NB 128
#define NI 1152
#define NJ 32
#define DM 16
#define JMSZ 512            // NJ*DM
#define BB 4                // batches register-blocked per wave
#define TPB 256
#define BPB ((TPB / 64) * BB)  // 16 batches per block

typedef unsigned short u16;
typedef u16 u16x8 __attribute__((ext_vector_type(8)));

__device__ __forceinline__ u16 f2bf(float x) {
  __hip_bfloat16 h = __float2bfloat16(x);     // RNE
  return *reinterpret_cast<u16*>(&h);
}
__device__ __forceinline__ float bf2f(u16 u) {
  unsigned int b = ((unsigned int)u) << 16;
  return __builtin_bit_cast(float, b);
}

template <int IC_, bool ATOMIC>
__global__ __launch_bounds__(TPB, 6) void caps_main(
    const float* __restrict__ u, const float* __restrict__ W,
    const float* __restrict__ bias, void* __restrict__ outv, int nchunk) {
  const int chunk = blockIdx.x;
  const int bg = blockIdx.y;
  const int tid = threadIdx.x;
  const int wid = __builtin_amdgcn_readfirstlane(tid >> 6);
  const int lane = tid & 63;
  const int j = lane >> 1;                    // parent capsule 0..31
  const int h = lane & 1;                     // m-octet
  const int b0 = __builtin_amdgcn_readfirstlane(bg * BPB + wid * BB);
  const int i0 = chunk * IC_;

  float acc[BB][8];
#pragma unroll
  for (int bb = 0; bb < BB; ++bb)
#pragma unroll
    for (int k = 0; k < 8; ++k) acc[bb][k] = 0.f;

  // per-lane W base for this (j,h): byte offset j*512 + h*32 within a tile
  const char* wbase = (const char*)W + (size_t)i0 * 16384 + j * 512 + h * 32;

  for (int t = 0; t < IC_; ++t) {
    const int i = i0 + t;
    const char* wp = wbase + (size_t)t * 16384;

    // u scalar loads (wave-uniform addresses -> SGPR path)
    float un[BB][8];
#pragma unroll
    for (int bb = 0; bb < BB; ++bb) {
      const float* up = u + ((size_t)(b0 + bb) * NI + i) * 8;
      float4 a0 = *(const float4*)up;
      float4 a1 = *(const float4*)(up + 4);
      un[bb][0] = a0.x; un[bb][1] = a0.y; un[bb][2] = a0.z; un[bb][3] = a0.w;
      un[bb][4] = a1.x; un[bb][5] = a1.y; un[bb][6] = a1.z; un[bb][7] = a1.w;
    }
    const float bj = bias[(size_t)i * NJ + j];

    float uh[BB][8];
#pragma unroll
    for (int bb = 0; bb < BB; ++bb)
#pragma unroll
      for (int k = 0; k < 8; ++k) uh[bb][k] = 0.f;

    // W loads in two up-front batches of 8 b128 (early issue, bounded regs)
#pragma unroll
    for (int half = 0; half < 2; ++half) {
      float4 w0[4], w1[4];
#pragma unroll
      for (int nn = 0; nn < 4; ++nn) {
        const int n = half * 4 + nn;
        w0[nn] = *(const float4*)(wp + n * 64);
        w1[nn] = *(const float4*)(wp + n * 64 + 16);
      }
#pragma unroll
      for (int nn = 0; nn < 4; ++nn) {
        const int n = half * 4 + nn;
#pragma unroll
        for (int bb = 0; bb < BB; ++bb) {
          const float uv = un[bb][n];
          uh[bb][0] = fmaf(uv, w0[nn].x, uh[bb][0]);
          uh[bb][1] = fmaf(uv, w0[nn].y, uh[bb][1]);
          uh[bb][2] = fmaf(uv, w0[nn].z, uh[bb][2]);
          uh[bb][3] = fmaf(uv, w0[nn].w, uh[bb][3]);
          uh[bb][4] = fmaf(uv, w1[nn].x, uh[bb][4]);
          uh[bb][5] = fmaf(uv, w1[nn].y, uh[bb][5]);
          uh[bb][6] = fmaf(uv, w1[nn].z, uh[bb][6]);
          uh[bb][7] = fmaf(uv, w1[nn].w, uh[bb][7]);
        }
      }
    }

    // agreement + MAX-FREE softmax over j, STAGE-MAJOR across batches.
    // lane = 2j+h: xor1 combines octets; xor2..32 sum e over the 32 j.
    float s2[BB], e[BB], es[BB];
#pragma unroll
    for (int bb = 0; bb < BB; ++bb) {
      float v = uh[bb][0] * uh[bb][0];
#pragma unroll
      for (int k = 1; k < 8; ++k) v = fmaf(uh[bb][k], uh[bb][k], v);
      s2[bb] = v;
    }
#pragma unroll
    for (int bb = 0; bb < BB; ++bb) s2[bb] += __shfl_xor(s2[bb], 1);
#pragma unroll
    for (int bb = 0; bb < BB; ++bb) e[bb] = __expf(s2[bb] * 0.25f);
#pragma unroll
    for (int bb = 0; bb < BB; ++bb) es[bb] = e[bb];
#pragma unroll
    for (int mask = 2; mask <= 32; mask <<= 1)
#pragma unroll
      for (int bb = 0; bb < BB; ++bb) es[bb] += __shfl_xor(es[bb], mask);
#pragma unroll
    for (int bb = 0; bb < BB; ++bb) {
      const float c = e[bb] * __builtin_amdgcn_rcpf(es[bb]) + bj;
#pragma unroll
      for (int k = 0; k < 8; ++k) acc[bb][k] = fmaf(c, uh[bb][k], acc[bb][k]);
    }
  }

#pragma unroll
  for (int bb = 0; bb < BB; ++bb) {
    if (ATOMIC) {
      float* p = (float*)outv + (size_t)(b0 + bb) * JMSZ + j * DM + h * 8;
#pragma unroll
      for (int k = 0; k < 8; ++k) atomicAdd(p + k, acc[bb][k]);
    } else {
      // bf16 partials: 16B per lane, lanes 2j+h contiguous -> 1KB/wave/bb
      u16* p = (u16*)outv + ((size_t)(b0 + bb) * nchunk + chunk) * JMSZ + j * DM + h * 8;
      u16x8 o8;
#pragma unroll
      for (int k = 0; k < 8; ++k) o8[k] = f2bf(acc[bb][k]);
      *(u16x8*)p = o8;
    }
  }
}

// Reduce bf16 chunk partials + squash. 8 q-threads per ushort8 unit
// (q = lane>>3 sums NSUM/8 chunks each; r = lane&7 -> 8 consecutive units,
// 128B-coalesced reads). q-combine via xor8/16/32; m-norm: 8 comps in-lane
// + xor1 (unit = half of one j's 16 m).
template <int NSUM>
__global__ __launch_bounds__(256) void caps_fin(const void* __restrict__ partv,
                                                float* __restrict__ v) {
  if constexpr (NSUM == 1) {
    const float* part = (const float*)partv;
    const int o = blockIdx.x * 256 + threadIdx.x;   // b*512 + j*16 + m
    const float s = part[o];
    float sq = s * s;                               // m = lane bits 0..3
    sq += __shfl_xor(sq, 1);
    sq += __shfl_xor(sq, 2);
    sq += __shfl_xor(sq, 4);
    sq += __shfl_xor(sq, 8);
    const float nrm = sqrtf(sq);
    v[o] = (sq / (1.0f + sq)) / (nrm + 1e-20f) * s;
  } else {
    const u16* part = (const u16*)partv;
    constexpr int QC = NSUM / 8;
    const int lane = threadIdx.x & 63;
    const int wv = (blockIdx.x * 256 + threadIdx.x) >> 6;  // global wave id
    const int q = lane >> 3;
    const int r = lane & 7;
    const int F = wv * 8 + r;                  // ushort8 unit: b*64 + jm8
    const int b = F >> 6;
    const int jm8 = F & 63;
    const u16* p = part + (size_t)b * NSUM * JMSZ + (size_t)q * QC * JMSZ + jm8 * 8;
    float s[8];
#pragma unroll
    for (int k = 0; k < 8; ++k) s[k] = 0.f;
#pragma unroll 4
    for (int cc = 0; cc < QC; ++cc) {
      u16x8 x = *(const u16x8*)(p + (size_t)cc * JMSZ);
#pragma unroll
      for (int k = 0; k < 8; ++k) s[k] += bf2f(x[k]);
    }
#pragma unroll
    for (int mask = 8; mask <= 32; mask <<= 1)   // combine 8 q-slices
#pragma unroll
      for (int k = 0; k < 8; ++k) s[k] += __shfl_xor(s[k], mask);
    float sq = s[0] * s[0];
#pragma unroll
    for (int k = 1; k < 8; ++k) sq = fmaf(s[k], s[k], sq);
    sq += __shfl_xor(sq, 1);                   // other half of this j's m
    const float nrm = sqrtf(sq);
    const float f = (sq / (1.0f + sq)) / (nrm + 1e-20f);
    if (q == 0) {
      float* vp = v + (size_t)F * 8;
      *(float4*)vp = make_float4(f * s[0], f * s[1], f * s[2], f * s[3]);
      *(float4*)(vp + 4) = make_float4(f * s[4], f * s[5], f * s[6], f * s[7]);
    }
  }
}

extern "C" void kernel_launch(void* const* d_in, const int* in_sizes, int n_in,
                              void* d_out, int out_size, void* d_ws, size_t ws_size,
                              hipStream_t stream) {
  const float* u = (const float*)d_in[0];
  const float* W = (const float*)d_in[1];
  const float* bias = (const float*)d_in[2];
  float* out = (float*)d_out;

  const size_t P192 = (size_t)NB * 192 * JMSZ * sizeof(u16);  // 24 MB
  const size_t P96 = (size_t)NB * 96 * JMSZ * sizeof(u16);    // 12 MB

  if (ws_size >= P192) {
    // grid (192,8)=1536 blocks, no LDS, VGPR<=85 -> 6 blocks/CU = 6 waves/SIMD
    caps_main<6, false><<<dim3(192, NB / BPB), TPB, 0, stream>>>(u, W, bias, d_ws, 192);
    caps_fin<192><<<256, 256, 0, stream>>>(d_ws, out);
  } else if (ws_size >= P96) {
    caps_main<12, false><<<dim3(96, NB / BPB), TPB, 0, stream>>>(u, W, bias, d_ws, 96);
    caps_fin<96><<<256, 256, 0, stream>>>(d_ws, out);
  } else {
    float* sbuf = (float*)d_ws;
    hipMemsetAsync(sbuf, 0, (size_t)NB * JMSZ * sizeof(float), stream);
    caps_main<18, true><<<dim3(64, NB / BPB), TPB, 0, stream>>>(u, W, bias, sbuf, 64);
    caps_fin<1><<<(NB * JMSZ) / 256, 256, 0, stream>>>(sbuf, out);
  }
}